// Round 8
// baseline (174.168 us; speedup 1.0000x reference)
//
#include <hip/hip_runtime.h>

// NodeClassifier 3-layer MP-GNN, MI355X. R8: gather concurrency 4x.
// R6/R7 showed layer_kernel latency-bound (VALU 12%, occ 11%): grid shape
// capped gather at ~10 waves/CU. Now 1024-thr blocks, 16 waves, 1 node/wave:
// 10000 gather waves (~32/CU, wave-slot limit). LDS 35.9KB -> 2 blocks/CU.
// esrc dummy-fill removed (clamp-select per slot instead).
// 5 dispatches: prep, place, L1 fused, L2 fused + chained L3, agg40.
// agg(x@W+b) == agg(x)@W + deg*b. Lessons: grid.sync ~35us (R3); single-block
// serial work = straggler (R4); dispatch overhead ~8-10us each (R2 vs R4).

#define N_NODES   10000
#define N_EDGES   320000
#define D_HID     256
#define N_CLASSES 40
#define CAP       96

typedef __attribute__((ext_vector_type(8))) short short8;
typedef __attribute__((ext_vector_type(4))) float f32x4;

__device__ __forceinline__ ushort f2bf(float f) {
    unsigned u = __float_as_uint(f);
    u = (u + 0x7fffu + ((u >> 16) & 1u)) >> 16;   // RNE; inputs finite
    return (ushort)u;
}
__device__ __forceinline__ float bf2f(ushort u) {
    return __uint_as_float(((unsigned)u) << 16);
}

// ---------------- prep: zero cursor, pad rows, bf16 conversions ----------------

__global__ __launch_bounds__(256)
void prep_kernel(const float* __restrict__ X,
                 const float* __restrict__ W1, const float* __restrict__ W2,
                 const float* __restrict__ W3,
                 ushort* __restrict__ Xb, ushort* __restrict__ bufY,
                 ushort* __restrict__ bufH,
                 ushort* __restrict__ W1b, ushort* __restrict__ W2b,
                 ushort* __restrict__ W3b, int* __restrict__ cursor) {
    const int tid  = blockIdx.x * 256 + threadIdx.x;
    const int nthr = gridDim.x * 256;
    for (int i = tid; i < N_NODES; i += nthr) cursor[i] = 0;
    // zero the padding rows (node index N_NODES used by clamp-select)
    ushort4 z; z.x = 0; z.y = 0; z.z = 0; z.w = 0;
    if (tid < 64) {
        ((ushort4*)Xb)[640000 + tid]   = z;   // row 10000 of Xb
        ((ushort4*)bufY)[640000 + tid] = z;   // row 10000 of bufY
    }
    if (tid < 10) ((ushort4*)bufH)[100000 + tid] = z;  // row 10000 of bufH
    // X -> bf16
    for (int i = tid; i < N_NODES * D_HID / 4; i += nthr) {
        float4 v = ((const float4*)X)[i];
        ushort4 o;
        o.x = f2bf(v.x); o.y = f2bf(v.y); o.z = f2bf(v.z); o.w = f2bf(v.w);
        ((ushort4*)Xb)[i] = o;
    }
    // weights -> bf16, transposed to n-major
    for (int i = tid; i < 141312; i += nthr) {
        if (i < 65536) {
            int n = i >> 8, k = i & 255;
            W1b[i] = f2bf(W1[k * 256 + n]);
        } else if (i < 131072) {
            int t2 = i - 65536;
            int n = t2 >> 8, k = t2 & 255;
            W2b[t2] = f2bf(W2[k * 256 + n]);
        } else {
            int t2 = i - 131072;
            int n = t2 >> 8, k = t2 & 255;
            W3b[t2] = f2bf(W3[k * N_CLASSES + n]);
        }
    }
}

// ---------------- place: bucket CSR via global atomics ----------------

__global__ __launch_bounds__(256)
void place_kernel(const int* __restrict__ edges, int* __restrict__ cursor,
                  int* __restrict__ esrc) {
    int e = blockIdx.x * 256 + threadIdx.x;
    if (e < N_EDGES) {
        int d = edges[N_EDGES + e];
        int pos = atomicAdd(&cursor[d], 1);
        if (pos < CAP) esrc[d * CAP + pos] = edges[e];
    }
}

// ---------------- fused layer: agg(16 nodes) -> LDS -> MFMA GEMM -> relu ----------------
// 1024 threads = 16 waves, 16 nodes/block, ONE node per wave (max gather
// concurrency). 625 blocks. GEMM: wave w -> cols w*16..+16 (1 MFMA/k-step).
// CHAIN: out2 tile stays in LDS -> @W3 + b3 -> h3 global (waves 0..2).

#define LDSA 264   // padded LDS row stride (bf16)

template<bool CHAIN>
__global__ __launch_bounds__(1024)
void layer_kernel(const ushort* __restrict__ Xin, const ushort* __restrict__ Bt,
                  const float* __restrict__ bias,
                  const int* __restrict__ deg, const int* __restrict__ esrc,
                  const ushort* __restrict__ W3b, const float* __restrict__ b3,
                  ushort* __restrict__ Out) {
    __shared__ ushort As[16 * LDSA];      // 8448 B; x_agg, reused as out2 when CHAIN
    __shared__ ushort Bs[40 * LDSA];      // 21120 B; main: [256 n][40-stride]; chain: W3
    __shared__ int    eidxL[16 * CAP];    // 6144 B
    __shared__ int    degI[16];
    __shared__ float  degF[16];

    const int tid = threadIdx.x;
    const int wave = tid >> 6, lane = tid & 63;
    const int lr = lane & 15, lg = lane >> 4;
    const int rowBase = blockIdx.x * 16;

    // ---- phase 0: stage edge lists + degrees ----
    {
        int idx = tid;                    // 16*96 = 1536 ints
        if (idx < 16 * CAP) eidxL[idx] = esrc[rowBase * CAP + idx];
        idx = 1024 + tid;
        if (idx < 16 * CAP) eidxL[idx] = esrc[rowBase * CAP + idx];
    }
    if (tid < 16) {
        int c = deg[rowBase + tid];
        degF[tid] = (float)c;             // true degree (bias term)
        degI[tid] = (c > CAP) ? CAP : c;
    }
    __syncthreads();

    // ---- phase 1: gather, one node per wave, batches of 8, clamp-select ----
    const uint2* hp = (const uint2*)Xin;
    {
        const int cnt  = degI[wave];
        const int cntp = (cnt + 7) & ~7;
        float a0 = 0.f, a1 = 0.f, a2 = 0.f, a3 = 0.f;
#pragma unroll 1
        for (int i = 0; i < cntp; i += 8) {
            uint2 v[8];
#pragma unroll
            for (int u = 0; u < 8; ++u) {
                int slot = i + u;
                int s = (slot < cnt) ? eidxL[wave * CAP + slot] : N_NODES;
                v[u] = hp[(size_t)s * 64 + lane];
            }
#pragma unroll
            for (int u = 0; u < 8; ++u) {
                a0 += bf2f((ushort)(v[u].x & 0xffff));
                a1 += bf2f((ushort)(v[u].x >> 16));
                a2 += bf2f((ushort)(v[u].y & 0xffff));
                a3 += bf2f((ushort)(v[u].y >> 16));
            }
        }
        uint2 o;
        o.x = (unsigned)f2bf(a0) | ((unsigned)f2bf(a1) << 16);
        o.y = (unsigned)f2bf(a2) | ((unsigned)f2bf(a3) << 16);
        *(uint2*)(As + wave * LDSA + lane * 4) = o;
    }

    // ---- phase 2: GEMM 16x256 @ 256x256, wave w -> 16 cols ----
    f32x4 acc = {};
    for (int k0 = 0; k0 < 256; k0 += 32) {
        __syncthreads();                   // As ready (k0=0) / Bs reads done (k0>0)
        {   // stage Bs: 256 n-rows x 32 k, 1024 x 16B chunks, one pass
            int n = tid >> 2, c = (tid & 3) * 8;
            *(uint4*)(Bs + n * 40 + c) = *(const uint4*)(Bt + (size_t)n * 256 + k0 + c);
        }
        __syncthreads();
        short8 af = *(const short8*)(As + lr * LDSA + k0 + lg * 8);
        short8 bf = *(const short8*)(Bs + (wave * 16 + lr) * 40 + lg * 8);
        acc = __builtin_amdgcn_mfma_f32_16x16x32_bf16(af, bf, acc, 0, 0, 0);
    }

    if (!CHAIN) {
        // epilogue: relu(acc + deg*b) -> bf16 global (625*16 = 10000, no mask)
        int col = wave * 16 + lr;
        float bv = bias[col];
#pragma unroll
        for (int r = 0; r < 4; ++r) {
            int grow = rowBase + lg * 4 + r;
            float dg = degF[lg * 4 + r];
            Out[(size_t)grow * 256 + col] = f2bf(fmaxf(fmaf(dg, bv, acc[r]), 0.f));
        }
    } else {
        __syncthreads();   // all As/Bs reads done before overwrite
        // out2 tile -> As (bf16), cols disjoint per wave
        {
            int col = wave * 16 + lr;
            float bv = bias[col];
#pragma unroll
            for (int r = 0; r < 4; ++r) {
                int rl = lg * 4 + r;
                As[rl * LDSA + col] = f2bf(fmaxf(fmaf(degF[rl], bv, acc[r]), 0.f));
            }
        }
        // stage W3 (40 n-rows x 256 k) into Bs[n*LDSA + k]: 1280 x 16B chunks
        {
            int idx = tid;
            if (idx < 1280) {
                int n = idx >> 5, c = (idx & 31) * 8;
                *(uint4*)(Bs + n * LDSA + c) = *(const uint4*)(W3b + (size_t)n * 256 + c);
            }
            idx = 1024 + tid;
            if (idx < 1280) {
                int n = idx >> 5, c = (idx & 31) * 8;
                *(uint4*)(Bs + n * LDSA + c) = *(const uint4*)(W3b + (size_t)n * 256 + c);
            }
        }
        __syncthreads();
        // gemm3: h3 = out2 @ W3 + b3 (waves 0..2 cover 48 cols, mask at 40)
        if (wave < 3) {
            f32x4 acc3 = {};
            for (int k0 = 0; k0 < 256; k0 += 32) {
                short8 af = *(const short8*)(As + lr * LDSA + k0 + lg * 8);
                short8 bf = *(const short8*)(Bs + (wave * 16 + lr) * LDSA + k0 + lg * 8);
                acc3 = __builtin_amdgcn_mfma_f32_16x16x32_bf16(af, bf, acc3, 0, 0, 0);
            }
            int col = wave * 16 + lr;
            if (col < N_CLASSES) {
                float bv = b3[col];
#pragma unroll
                for (int r = 0; r < 4; ++r) {
                    int grow = rowBase + lg * 4 + r;
                    Out[(size_t)grow * N_CLASSES + col] = f2bf(acc3[r] + bv);
                }
            }
        }
    }
}

// ---------------- agg40: out = relu(segsum(h3[src])) -> f32 ----------------

__global__ __launch_bounds__(256)
void agg_relu_40_kernel(const ushort* __restrict__ h, const int* __restrict__ deg,
                        const int* __restrict__ esrc, float* __restrict__ out) {
    int wv   = threadIdx.x >> 6;
    int lane = threadIdx.x & 63;
    int node = (blockIdx.x << 2) + wv;
    if (node >= N_NODES) return;
    int cnt = deg[node];
    if (cnt > CAP) cnt = CAP;
    int cntp = (cnt + 7) & ~7;
    const int* ep = esrc + node * CAP;
    if (lane < N_CLASSES) {
        float a = 0.f, b = 0.f;
#pragma unroll 1
        for (int i = 0; i < cntp; i += 8) {
            int s[8];
#pragma unroll
            for (int u = 0; u < 8; ++u) s[u] = (i + u < cnt) ? ep[i + u] : N_NODES;
#pragma unroll
            for (int u = 0; u < 8; u += 2) {
                a += bf2f(h[(size_t)s[u]     * N_CLASSES + lane]);
                b += bf2f(h[(size_t)s[u + 1] * N_CLASSES + lane]);
            }
        }
        out[(size_t)node * N_CLASSES + lane] = fmaxf(a + b, 0.f);
    }
}

// ---------------- launch ----------------

extern "C" void kernel_launch(void* const* d_in, const int* in_sizes, int n_in,
                              void* d_out, int out_size, void* d_ws, size_t ws_size,
                              hipStream_t stream) {
    const float* X     = (const float*)d_in[0];
    const int*   edges = (const int*)d_in[1];
    const float* W1 = (const float*)d_in[2];
    const float* b1 = (const float*)d_in[3];
    const float* W2 = (const float*)d_in[4];
    const float* b2 = (const float*)d_in[5];
    const float* W3 = (const float*)d_in[6];
    const float* b3 = (const float*)d_in[7];
    float* out = (float*)d_out;

    char* ws = (char*)d_ws;
    ushort* Xb   = (ushort*)(ws);                    //  5,120,512 B (10001 rows x 256)
    ushort* bufY = (ushort*)(ws + 5120512);          //  5,120,512 B (10001 rows)
    ushort* bufH = (ushort*)(ws + 10241024);         //    800,080 B (10001 rows x 40)
    ushort* W1b  = (ushort*)(ws + 11041104);         //    131,072 B (n-major)
    ushort* W2b  = (ushort*)(ws + 11172176);         //    131,072 B
    ushort* W3b  = (ushort*)(ws + 11303248);         //     20,480 B
    int*   cursor = (int*)(ws + 11323728);           //     40,000 B (== deg after place)
    int*   esrc   = (int*)(ws + 11363728);           //  3,840,000 B (10000 x 96)

    // 1: conversions + zero cursor + zero pad rows
    prep_kernel<<<512, 256, 0, stream>>>(X, W1, W2, W3, Xb, bufY, bufH,
                                         W1b, W2b, W3b, cursor);
    // 2: bucket-CSR place
    place_kernel<<<(N_EDGES + 255) / 256, 256, 0, stream>>>(edges, cursor, esrc);
    // 3: layer 1 fused (agg + GEMM + relu)
    layer_kernel<false><<<N_NODES / 16, 1024, 0, stream>>>(
        Xb, W1b, b1, cursor, esrc, W3b, b3, bufY);
    // 4: layer 2 fused + chained layer-3 transform (h3 = out2@W3 + b3)
    layer_kernel<true><<<N_NODES / 16, 1024, 0, stream>>>(
        bufY, W2b, b2, cursor, esrc, W3b, b3, bufH);
    // 5: final aggregation + relu -> d_out (f32)
    agg_relu_40_kernel<<<(N_NODES + 3) / 4, 256, 0, stream>>>(bufH, cursor, esrc, out);
}